// Round 21
// baseline (45.033 us; speedup 1.0000x reference)
//
#include <hip/hip_runtime.h>
#include <hip/hip_fp16.h>
#include <math.h>

// Problem constants: B=2, K=128, L=4096, DK=DL=128, HID=128
constexpr int BB = 2;
constexpr int KK = 128;
constexpr int LL = 4096;
constexpr int DD = 128;
constexpr int HH = 128;

typedef _Float16 f16x2 __attribute__((ext_vector_type(2)));

__device__ __forceinline__ float4 ld4(const float* p) {
    return *reinterpret_cast<const float4*>(p);
}

// pack two floats into a half2 dword
__device__ __forceinline__ uint32_t pkh2(float a, float b) {
    return __builtin_bit_cast(uint32_t, __floats2half2_rn(a, b));
}

// duplicate fp16(x) into both halves of a dword
__device__ __forceinline__ uint32_t duph(float x) {
    __half h = __float2half(x);
    unsigned short us = __builtin_bit_cast(unsigned short, h);
    return (uint32_t)us * 0x10001u;
}

// ---------------------------------------------------------------------------
// vT2 layout: dword(b, g, lp, ph) = ((b*8 + g)*2048 + lp)*16 + ph
//   g = h/16, ph = h%16, lp = l/2; dword = half2(v[2lp][h], v[2lp+1][h]).
// ---------------------------------------------------------------------------

// ---------------------------------------------------------------------------
// K1 (R19 verbatim + counter zeroing): grid 288 x 256 threads.
//  bid<256: B-tile 32 rows, XCD-swizzled (writer XCD = l-chunk&7 = k2 reader).
//  bid>=256: A-tile 8 rows. Block 287 also zeroes the 64 sync counters.
// W1-half staged into LDS in two 32 KB chunks; f32 math (proven numerics).
// ---------------------------------------------------------------------------
__global__ __launch_bounds__(256) void k1_gemm(
    const float* __restrict__ inA, const float* __restrict__ inB,
    const float* __restrict__ W1, const float* __restrict__ b1,
    const float* __restrict__ w2,
    uint32_t* __restrict__ u_dup, uint32_t* __restrict__ w2_dup,
    uint32_t* __restrict__ vT2, int* __restrict__ sync_ctrs)
{
    __shared__ __align__(16) char smem[48 * 1024];
    float*  sIn = reinterpret_cast<float*>(smem);               // <=16 KiB
    float4* sW4 = reinterpret_cast<float4*>(smem + 16 * 1024);  // 32 KiB

    const int bid = blockIdx.x;
    const int tid = threadIdx.x;

    if (bid == 287 && tid < 64) sync_ctrs[tid] = 0;   // arrive[32] + done[32]

    int row0, rows;
    bool isA;
    if (bid < 256) {
        const int x = bid & 7, y = bid >> 3;
        const int C = x + 8 * (y & 1);
        row0 = C * 512 + (y >> 1) * 32;    // B virtual row (b*4096 + l)
        rows = 32; isA = false;
    } else {
        row0 = (bid - 256) * 8;            // u row
        rows = 8;  isA = true;
    }
    const float* src = (isA ? inA : inB) + (size_t)row0 * DD;
    const float4* wsrc = reinterpret_cast<const float4*>(W1 + (isA ? 0 : DD * HH));

    for (int n = tid; n < rows * 32; n += 256)
        reinterpret_cast<float4*>(sIn)[n] =
            reinterpret_cast<const float4*>(src)[n];

    const int tx = tid & 31;   // h-cols tx*4 .. tx*4+3
    const int ty = tid >> 5;   // row group: rows ty*4 .. ty*4+3
    const bool active = (ty * 4 + 3) < rows;

    float acc[4][4];
    #pragma unroll
    for (int r = 0; r < 4; ++r)
        #pragma unroll
        for (int c = 0; c < 4; ++c) acc[r][c] = 0.f;

    for (int wh = 0; wh < 2; ++wh) {
        __syncthreads();
        #pragma unroll
        for (int q = 0; q < 8; ++q)
            sW4[tid + 256 * q] = wsrc[wh * 2048 + tid + 256 * q];
        __syncthreads();

        if (active) {
            #pragma unroll 2
            for (int dd0 = 0; dd0 < 64; dd0 += 4) {
                const int d0 = wh * 64 + dd0;
                float4 w4[4];
                #pragma unroll
                for (int dd = 0; dd < 4; ++dd)
                    w4[dd] = sW4[(dd0 + dd) * 32 + tx];
                float a[4][4];
                #pragma unroll
                for (int r = 0; r < 4; ++r) {
                    float4 a4 = ld4(&sIn[(ty * 4 + r) * 128 + d0]);
                    a[r][0] = a4.x; a[r][1] = a4.y; a[r][2] = a4.z; a[r][3] = a4.w;
                }
                #pragma unroll
                for (int dd = 0; dd < 4; ++dd) {
                    const float4 wv = w4[dd];
                    #pragma unroll
                    for (int r = 0; r < 4; ++r) {
                        const float av = a[r][dd];
                        acc[r][0] = fmaf(av, wv.x, acc[r][0]);
                        acc[r][1] = fmaf(av, wv.y, acc[r][1]);
                        acc[r][2] = fmaf(av, wv.z, acc[r][2]);
                        acc[r][3] = fmaf(av, wv.w, acc[r][3]);
                    }
                }
            }
        }
    }

    if (isA) {
        if (active) {
            const float4 bb = ld4(&b1[tx * 4]);
            #pragma unroll
            for (int r = 0; r < 4; ++r) {
                uint4 o;
                o.x = duph(acc[r][0] + bb.x);
                o.y = duph(acc[r][1] + bb.y);
                o.z = duph(acc[r][2] + bb.z);
                o.w = duph(acc[r][3] + bb.w);
                *reinterpret_cast<uint4*>(
                    &u_dup[(size_t)(row0 + ty * 4 + r) * HH + tx * 4]) = o;
            }
        }
        if (bid == 256 && tid < HH) w2_dup[tid] = duph(w2[tid]);
    } else {
        const int bsel = row0 >> 12;
        const int lp0  = ((row0 & 4095) + ty * 4) >> 1;
        uint32_t* vb = vT2 + (size_t)bsel * (8 * 2048 * 16);
        #pragma unroll
        for (int c = 0; c < 4; ++c) {
            const int h = tx * 4 + c, g = h >> 4, ph = h & 15;
            uint32_t* dst = vb + ((size_t)g * 2048 + lp0) * 16 + ph;
            dst[0]  = pkh2(acc[0][c], acc[1][c]);
            dst[16] = pkh2(acc[2][c], acc[3][c]);
        }
    }
}

// ---------------------------------------------------------------------------
// K2: scores + exp + softmax via per-group 8-way flag sync. 256 blocks x 512
// threads (capacity >= 2 blocks/CU -> all 256 blocks dispatch immediately,
// so sibling spins always resolve).
// Block m = cb + 8*(kt + 16*b), m < 256; group grp = b*16+kt (32 groups of
// 8 cb-siblings). Inner loop = R15 verbatim. After scores: exp in registers,
// per-k block partials -> psum[grp][k][cb] (disjoint, deterministic),
// release-increment arrive[grp]; spin arrive==8; fixed-order sum; scale
// registers; single coalesced d_out write. Last-done block resets counters.
// ---------------------------------------------------------------------------
__global__ __launch_bounds__(512) void k2_fused(
    const uint32_t* __restrict__ u_dup, const uint32_t* __restrict__ w2_dup,
    const uint32_t* __restrict__ vT2, float* __restrict__ psum,
    int* __restrict__ arrive, int* __restrict__ done,
    float* __restrict__ out)
{
    __shared__ __align__(16) uint32_t sU[8 * HH];   // 4 KiB
    __shared__ __align__(16) uint32_t sW[HH];       // 512 B
    __shared__ float red[8][4];
    __shared__ float sS[8];

    int m = blockIdx.x;
    const int cb = m & 7;   m >>= 3;
    const int kt = m & 15;  m >>= 4;
    const int b  = m;
    const int tid = threadIdx.x;
    const int grp = b * 16 + kt;

    if (tid < 256)
        reinterpret_cast<uint4*>(sU)[tid] =
            reinterpret_cast<const uint4*>(u_dup + (size_t)(b * KK + kt * 8) * HH)[tid];
    else if (tid < 288)
        reinterpret_cast<uint4*>(sW)[tid - 256] =
            reinterpret_cast<const uint4*>(w2_dup)[tid - 256];
    __syncthreads();

    const int kh = tid >> 8;        // 0/1 -> k rows kt*8 + kh*4 .. +3
    const int t  = tid & 255;
    const int lp = cb * 256 + t;    // l-pair within b

    const uint4* vg = reinterpret_cast<const uint4*>(
                          vT2 + ((size_t)b * 8 * 2048 + lp) * 16);
    const uint4* su4 = reinterpret_cast<const uint4*>(sU + kh * 4 * HH);
    const uint4* sw4 = reinterpret_cast<const uint4*>(sW);

    const f16x2 hz = { (_Float16)0, (_Float16)0 };
    float2 facc[4];
    #pragma unroll
    for (int k = 0; k < 4; ++k) { facc[k].x = 0.f; facc[k].y = 0.f; }

    #pragma unroll
    for (int g = 0; g < 8; ++g) {          // 16 h per group, 64 B contiguous
        uint4 vq[4];
        #pragma unroll
        for (int c = 0; c < 4; ++c)
            vq[c] = vg[(size_t)g * 8192 + c];
        const uint32_t* vd = reinterpret_cast<const uint32_t*>(vq);

        uint4 wq[4];
        #pragma unroll
        for (int c = 0; c < 4; ++c) wq[c] = sw4[g * 4 + c];
        const uint32_t* wd = reinterpret_cast<const uint32_t*>(wq);

        f16x2 hacc[4] = { hz, hz, hz, hz };
        #pragma unroll
        for (int k = 0; k < 4; ++k) {
            uint4 uq[4];
            #pragma unroll
            for (int c = 0; c < 4; ++c) uq[c] = su4[k * 32 + g * 4 + c];
            const uint32_t* ud = reinterpret_cast<const uint32_t*>(uq);
            #pragma unroll
            for (int ph = 0; ph < 16; ++ph) {
                f16x2 vv = __builtin_bit_cast(f16x2, vd[ph]);
                f16x2 uu = __builtin_bit_cast(f16x2, ud[ph]);
                f16x2 ww = __builtin_bit_cast(f16x2, wd[ph]);
                f16x2 s = vv + uu;
                s = __builtin_elementwise_max(s, hz);
                hacc[k] = s * ww + hacc[k];
            }
        }
        #pragma unroll
        for (int k = 0; k < 4; ++k) {
            facc[k].x += (float)hacc[k].x;
            facc[k].y += (float)hacc[k].y;
        }
    }

    // ---- exp in registers (max-free: |s| <~ 2, f32 exp headroom is huge) ----
    float2 te[4];
    #pragma unroll
    for (int k = 0; k < 4; ++k) {
        te[k].x = expf(facc[k].x);
        te[k].y = expf(facc[k].y);
    }

    // ---- block partial sums per k-row ----
    const int wave = tid >> 6, lane = tid & 63;
    float ps[4];
    #pragma unroll
    for (int k = 0; k < 4; ++k) {
        ps[k] = te[k].x + te[k].y;
        #pragma unroll
        for (int off = 32; off > 0; off >>= 1)
            ps[k] += __shfl_xor(ps[k], off, 64);
    }
    if (lane == 0) {
        red[wave][0] = ps[0]; red[wave][1] = ps[1];
        red[wave][2] = ps[2]; red[wave][3] = ps[3];
    }
    __syncthreads();
    if (tid < 8) {
        const int khh = tid >> 2, kk = tid & 3;
        const float S = (red[khh * 4 + 0][kk] + red[khh * 4 + 1][kk])
                      + (red[khh * 4 + 2][kk] + red[khh * 4 + 3][kk]);
        psum[(size_t)(grp * 8 + khh * 4 + kk) * 8 + cb] = S;
    }
    __syncthreads();

    // ---- 8-way group sync: release partials, spin until all 8 arrived ----
    if (tid == 0) {
        __threadfence();
        __hip_atomic_fetch_add(&arrive[grp], 1, __ATOMIC_ACQ_REL,
                               __HIP_MEMORY_SCOPE_AGENT);
        while (__hip_atomic_load(&arrive[grp], __ATOMIC_ACQUIRE,
                                 __HIP_MEMORY_SCOPE_AGENT) < 8)
            __builtin_amdgcn_s_sleep(1);
    }
    __syncthreads();

    // ---- fixed-order combine (deterministic) ----
    if (tid < 8) {
        float S = 0.f;
        #pragma unroll
        for (int c = 0; c < 8; ++c)
            S += __hip_atomic_load(&psum[(size_t)(grp * 8 + tid) * 8 + c],
                                   __ATOMIC_RELAXED, __HIP_MEMORY_SCOPE_AGENT);
        sS[tid] = S;
    }
    __syncthreads();

    // ---- scale + single write of d_out ----
    #pragma unroll
    for (int k = 0; k < 4; ++k) {
        const float inv = 1.0f / sS[kh * 4 + k];
        float2 o;
        o.x = te[k].x * inv;
        o.y = te[k].y * inv;
        *reinterpret_cast<float2*>(
            &out[(size_t)(b * KK + kt * 8 + kh * 4 + k) * LL + 2 * lp]) = o;
    }

    // ---- self-reset for the next graph replay ----
    if (tid == 0) {
        const int d = __hip_atomic_fetch_add(&done[grp], 1, __ATOMIC_ACQ_REL,
                                             __HIP_MEMORY_SCOPE_AGENT);
        if (d == 7) {   // last sibling: everyone else has exited their spin
            __hip_atomic_store(&arrive[grp], 0, __ATOMIC_RELAXED,
                               __HIP_MEMORY_SCOPE_AGENT);
            __hip_atomic_store(&done[grp], 0, __ATOMIC_RELAXED,
                               __HIP_MEMORY_SCOPE_AGENT);
        }
    }
}

// ---------------------------------------------------------------------------
extern "C" void kernel_launch(void* const* d_in, const int* in_sizes, int n_in,
                              void* d_out, int out_size, void* d_ws, size_t ws_size,
                              hipStream_t stream)
{
    const float* inA = (const float*)d_in[0];
    const float* inB = (const float*)d_in[1];
    const float* W1  = (const float*)d_in[2];
    const float* b1  = (const float*)d_in[3];
    const float* w2  = (const float*)d_in[4];
    float* out = (float*)d_out;

    char* ws = (char*)d_ws;
    uint32_t* u_dup  = (uint32_t*)ws;                      // 128 KiB
    uint32_t* w2_dup = (uint32_t*)(ws + 0x20000);          // 512 B
    uint32_t* vT2    = (uint32_t*)(ws + 0x40000);          // 2 MiB -> 0x240000
    float*    psum   = (float*)(ws + 0x240000);            // 8 KiB (32*8*8)
    int*      ctrs   = (int*)(ws + 0x242000);              // arrive[32]+done[32]
    int*      arrive = ctrs;
    int*      done   = ctrs + 32;

    hipLaunchKernelGGL(k1_gemm, dim3(288), dim3(256), 0, stream,
                       inA, inB, W1, b1, w2, u_dup, w2_dup, vT2, ctrs);
    hipLaunchKernelGGL(k2_fused, dim3(256), dim3(512), 0, stream,
                       u_dup, w2_dup, vT2, psum, arrive, done, out);
}

// Round 22
// 27.841 us; speedup vs baseline: 1.6175x; 1.6175x over previous
//
#include <hip/hip_runtime.h>
#include <hip/hip_fp16.h>
#include <math.h>

// Problem constants: B=2, K=128, L=4096, DK=DL=128, HID=128
constexpr int BB = 2;
constexpr int KK = 128;
constexpr int LL = 4096;
constexpr int DD = 128;
constexpr int HH = 128;

typedef _Float16 f16x2 __attribute__((ext_vector_type(2)));

__device__ __forceinline__ float4 ld4(const float* p) {
    return *reinterpret_cast<const float4*>(p);
}

// pack two floats into a half2 dword
__device__ __forceinline__ uint32_t pkh2(float a, float b) {
    return __builtin_bit_cast(uint32_t, __floats2half2_rn(a, b));
}

// duplicate fp16(x) into both halves of a dword
__device__ __forceinline__ uint32_t duph(float x) {
    __half h = __float2half(x);
    unsigned short us = __builtin_bit_cast(unsigned short, h);
    return (uint32_t)us * 0x10001u;
}

// ---------------------------------------------------------------------------
// vT2 layout: dword(b, g, lp, ph) = ((b*8 + g)*2048 + lp)*16 + ph
//   g = h/16, ph = h%16, lp = l/2; dword = half2(v[2lp][h], v[2lp+1][h]).
// A thread's 16-h group at fixed lp is 64 B CONTIGUOUS.
// ---------------------------------------------------------------------------

// ---------------------------------------------------------------------------
// K1: grid 288 x 256 threads.
//  bid<256: B-tile, 32 rows, XCD-swizzled (writer XCD = l-chunk&7 = k2 reader).
//  bid>=256: A-tile, 8 rows (32 small blocks; doubled-up CUs get a short tail).
// W1-half staged into LDS in two 32 KB chunks; f32 math (proven numerics).
// ---------------------------------------------------------------------------
__global__ __launch_bounds__(256) void k1_gemm(
    const float* __restrict__ inA, const float* __restrict__ inB,
    const float* __restrict__ W1, const float* __restrict__ b1,
    const float* __restrict__ w2,
    uint32_t* __restrict__ u_dup, uint32_t* __restrict__ w2_dup,
    uint32_t* __restrict__ vT2)
{
    __shared__ __align__(16) char smem[48 * 1024];
    float*  sIn = reinterpret_cast<float*>(smem);               // <=16 KiB
    float4* sW4 = reinterpret_cast<float4*>(smem + 16 * 1024);  // 32 KiB

    const int bid = blockIdx.x;
    const int tid = threadIdx.x;

    int row0, rows;
    bool isA;
    if (bid < 256) {
        const int x = bid & 7, y = bid >> 3;
        const int C = x + 8 * (y & 1);
        row0 = C * 512 + (y >> 1) * 32;    // B virtual row (b*4096 + l)
        rows = 32; isA = false;
    } else {
        row0 = (bid - 256) * 8;            // u row
        rows = 8;  isA = true;
    }
    const float* src = (isA ? inA : inB) + (size_t)row0 * DD;
    const float4* wsrc = reinterpret_cast<const float4*>(W1 + (isA ? 0 : DD * HH));

    // stage input rows (rows*32 float4, coalesced)
    for (int n = tid; n < rows * 32; n += 256)
        reinterpret_cast<float4*>(sIn)[n] =
            reinterpret_cast<const float4*>(src)[n];

    const int tx = tid & 31;   // h-cols tx*4 .. tx*4+3
    const int ty = tid >> 5;   // row group: rows ty*4 .. ty*4+3
    const bool active = (ty * 4 + 3) < rows;

    float acc[4][4];           // [row r][h-col c]
    #pragma unroll
    for (int r = 0; r < 4; ++r)
        #pragma unroll
        for (int c = 0; c < 4; ++c) acc[r][c] = 0.f;

    for (int wh = 0; wh < 2; ++wh) {
        __syncthreads();
        #pragma unroll
        for (int q = 0; q < 8; ++q)
            sW4[tid + 256 * q] = wsrc[wh * 2048 + tid + 256 * q];
        __syncthreads();

        if (active) {
            #pragma unroll 2
            for (int dd0 = 0; dd0 < 64; dd0 += 4) {
                const int d0 = wh * 64 + dd0;
                float4 w4[4];
                #pragma unroll
                for (int dd = 0; dd < 4; ++dd)
                    w4[dd] = sW4[(dd0 + dd) * 32 + tx];
                float a[4][4];
                #pragma unroll
                for (int r = 0; r < 4; ++r) {
                    float4 a4 = ld4(&sIn[(ty * 4 + r) * 128 + d0]);
                    a[r][0] = a4.x; a[r][1] = a4.y; a[r][2] = a4.z; a[r][3] = a4.w;
                }
                #pragma unroll
                for (int dd = 0; dd < 4; ++dd) {
                    const float4 wv = w4[dd];
                    #pragma unroll
                    for (int r = 0; r < 4; ++r) {
                        const float av = a[r][dd];
                        acc[r][0] = fmaf(av, wv.x, acc[r][0]);
                        acc[r][1] = fmaf(av, wv.y, acc[r][1]);
                        acc[r][2] = fmaf(av, wv.z, acc[r][2]);
                        acc[r][3] = fmaf(av, wv.w, acc[r][3]);
                    }
                }
            }
        }
    }

    if (isA) {
        if (active) {
            const float4 bb = ld4(&b1[tx * 4]);
            #pragma unroll
            for (int r = 0; r < 4; ++r) {
                uint4 o;
                o.x = duph(acc[r][0] + bb.x);
                o.y = duph(acc[r][1] + bb.y);
                o.z = duph(acc[r][2] + bb.z);
                o.w = duph(acc[r][3] + bb.w);
                *reinterpret_cast<uint4*>(
                    &u_dup[(size_t)(row0 + ty * 4 + r) * HH + tx * 4]) = o;
            }
        }
        if (bid == 256 && tid < HH) w2_dup[tid] = duph(w2[tid]);
    } else {
        // direct register -> vT2 stores (8 dwords; lines fully written per wave)
        const int bsel = row0 >> 12;
        const int lp0  = ((row0 & 4095) + ty * 4) >> 1;   // 2 lp: lp0, lp0+1
        uint32_t* vb = vT2 + (size_t)bsel * (8 * 2048 * 16);
        #pragma unroll
        for (int c = 0; c < 4; ++c) {
            const int h = tx * 4 + c, g = h >> 4, ph = h & 15;
            uint32_t* dst = vb + ((size_t)g * 2048 + lp0) * 16 + ph;
            dst[0]  = pkh2(acc[0][c], acc[1][c]);   // lp0   : (l, l+1)
            dst[16] = pkh2(acc[2][c], acc[3][c]);   // lp0+1 : (l+2, l+3)
        }
    }
}

// ---------------------------------------------------------------------------
// K2 (R15 verbatim — proven): 256 blocks x 512 threads (1 block/CU).
// Block m = cb + 8*(kt + 16*b): reader XCD cb == writer XCD.
// kh = tid>>8 picks 4 k; t = tid&255 picks lp. u (8 rows) + w2 in LDS;
// v: 4 contiguous b128 per 16-h group; fp16 pk math, f32 flush per group.
// ---------------------------------------------------------------------------
__global__ __launch_bounds__(512) void k2_score(
    const uint32_t* __restrict__ u_dup, const uint32_t* __restrict__ w2_dup,
    const uint32_t* __restrict__ vT2, float* __restrict__ out)
{
    __shared__ __align__(16) uint32_t sU[8 * HH];   // 4 KiB
    __shared__ __align__(16) uint32_t sW[HH];       // 512 B

    int m = blockIdx.x;
    const int cb = m & 7;   m >>= 3;
    const int kt = m & 15;  m >>= 4;
    const int b  = m;
    const int tid = threadIdx.x;

    if (tid < 256)
        reinterpret_cast<uint4*>(sU)[tid] =
            reinterpret_cast<const uint4*>(u_dup + (size_t)(b * KK + kt * 8) * HH)[tid];
    else if (tid < 288)
        reinterpret_cast<uint4*>(sW)[tid - 256] =
            reinterpret_cast<const uint4*>(w2_dup)[tid - 256];
    __syncthreads();

    const int kh = tid >> 8;        // 0/1 -> k rows kt*8 + kh*4 .. +3
    const int t  = tid & 255;
    const int lp = cb * 256 + t;    // l-pair within b

    const uint4* vg = reinterpret_cast<const uint4*>(
                          vT2 + ((size_t)b * 8 * 2048 + lp) * 16);
    const uint4* su4 = reinterpret_cast<const uint4*>(sU + kh * 4 * HH);
    const uint4* sw4 = reinterpret_cast<const uint4*>(sW);

    const f16x2 hz = { (_Float16)0, (_Float16)0 };
    float2 facc[4];
    #pragma unroll
    for (int k = 0; k < 4; ++k) { facc[k].x = 0.f; facc[k].y = 0.f; }

    #pragma unroll
    for (int g = 0; g < 8; ++g) {          // 16 h per group, 64 B contiguous
        uint4 vq[4];
        #pragma unroll
        for (int c = 0; c < 4; ++c)
            vq[c] = vg[(size_t)g * 8192 + c];      // 8192 uint4 = 2048 lp * 64 B
        const uint32_t* vd = reinterpret_cast<const uint32_t*>(vq);

        uint4 wq[4];
        #pragma unroll
        for (int c = 0; c < 4; ++c) wq[c] = sw4[g * 4 + c];
        const uint32_t* wd = reinterpret_cast<const uint32_t*>(wq);

        f16x2 hacc[4] = { hz, hz, hz, hz };
        #pragma unroll
        for (int k = 0; k < 4; ++k) {
            uint4 uq[4];
            #pragma unroll
            for (int c = 0; c < 4; ++c) uq[c] = su4[k * 32 + g * 4 + c];
            const uint32_t* ud = reinterpret_cast<const uint32_t*>(uq);
            #pragma unroll
            for (int ph = 0; ph < 16; ++ph) {
                f16x2 vv = __builtin_bit_cast(f16x2, vd[ph]);
                f16x2 uu = __builtin_bit_cast(f16x2, ud[ph]);
                f16x2 ww = __builtin_bit_cast(f16x2, wd[ph]);
                f16x2 s = vv + uu;                          // v_pk_add_f16
                s = __builtin_elementwise_max(s, hz);       // v_pk_max_f16
                hacc[k] = s * ww + hacc[k];                 // v_pk_fma_f16
            }
        }
        #pragma unroll
        for (int k = 0; k < 4; ++k) {
            facc[k].x += (float)hacc[k].x;
            facc[k].y += (float)hacc[k].y;
        }
    }

    #pragma unroll
    for (int k = 0; k < 4; ++k)
        *reinterpret_cast<float2*>(
            &out[(size_t)(b * KK + kt * 8 + kh * 4 + k) * LL + 2 * lp]) = facc[k];
}

// ---------------------------------------------------------------------------
// K3: in-place row softmax WITHOUT max subtraction (|s| <~ 2; f32 exp has
// huge headroom; exp(s)/sum == softmax exactly). 256 blocks x 1024 threads.
// ---------------------------------------------------------------------------
__global__ __launch_bounds__(1024) void k3_softmax(float* __restrict__ out)
{
    __shared__ float reds[16];

    const int row = blockIdx.x;
    float* p = out + (size_t)row * LL;
    const int tid = threadIdx.x;

    float4 x = reinterpret_cast<const float4*>(p)[tid];

    x.x = expf(x.x); x.y = expf(x.y);
    x.z = expf(x.z); x.w = expf(x.w);
    float s = (x.x + x.y) + (x.z + x.w);
    #pragma unroll
    for (int off = 32; off > 0; off >>= 1)
        s += __shfl_xor(s, off, 64);
    const int lane = tid & 63, wv = tid >> 6;
    if (lane == 0) reds[wv] = s;
    __syncthreads();
    if (tid < 16) {
        float ss = reds[tid];
        #pragma unroll
        for (int off = 8; off > 0; off >>= 1)
            ss += __shfl_xor(ss, off, 64);
        reds[tid] = ss;
    }
    __syncthreads();
    s = reds[0];

    const float inv = 1.0f / s;
    x.x *= inv; x.y *= inv; x.z *= inv; x.w *= inv;
    reinterpret_cast<float4*>(p)[tid] = x;
}

// ---------------------------------------------------------------------------
extern "C" void kernel_launch(void* const* d_in, const int* in_sizes, int n_in,
                              void* d_out, int out_size, void* d_ws, size_t ws_size,
                              hipStream_t stream)
{
    const float* inA = (const float*)d_in[0];
    const float* inB = (const float*)d_in[1];
    const float* W1  = (const float*)d_in[2];
    const float* b1  = (const float*)d_in[3];
    const float* w2  = (const float*)d_in[4];
    float* out = (float*)d_out;

    char* ws = (char*)d_ws;
    uint32_t* u_dup  = (uint32_t*)ws;                      // 128 KiB
    uint32_t* w2_dup = (uint32_t*)(ws + 0x20000);          // 512 B
    uint32_t* vT2    = (uint32_t*)(ws + 0x40000);          // 2 MiB

    hipLaunchKernelGGL(k1_gemm, dim3(288), dim3(256), 0, stream,
                       inA, inB, W1, b1, w2, u_dup, w2_dup, vT2);
    hipLaunchKernelGGL(k2_score, dim3(256), dim3(512), 0, stream,
                       u_dup, w2_dup, vT2, out);
    hipLaunchKernelGGL(k3_softmax, dim3(BB * KK), dim3(1024), 0, stream, out);
}